// Round 6
// baseline (117.197 us; speedup 1.0000x reference)
//
#include <hip/hip_runtime.h>
#include <math.h>

// PinSAGE fused pipeline, r6: weight-stationary register-resident K1/K5.
// D=U=E=128, T=20 fixed; N, V from in_sizes.
//
// K0 prep:   WqT/WnT/WwT/WgT = bf16 transpose of weights (WT[n][k])
// K1 reg:    H = relu(table @ Wn + bn) -> bf16 [V][128]   (blocks < splitH)
//            nodeh = relu(table[node_ids] @ Wq + bq) -> nh[:,0:128] (rest)
//            W in 128 VGPRs (32 frags), wave-autonomous 16-row tiles,
//            NO LDS / NO barriers in the loop, line-coalesced direct loads.
// K2 agg:    nh[:,128:256] = sum_t alpha * H[neigh]       (gather-FMA)
// K3 emb:    embb = relu(nh @ Ww + bw) bf16 + sumsq partials (r2/r5 kernel)
// K4 norm:   scale = 1/||emb||_F
// K5 reg:    out = relu(scale*(embb @ Wg) + bg) fp32, W-register-resident.
//
// MFMA orientation (verified r3/r5): acc[mt] = mfma(wfrag, afrag, acc) ->
// lane l holds C[row = tile*16 + (l&15)][cols 16*mt + 4*(l>>4) + i].

using f32x4  = __attribute__((ext_vector_type(4))) float;
using short8 = __attribute__((ext_vector_type(8))) short;   // 8 bf16

__device__ __forceinline__ ushort f2bf(float f) {
    uint u = __float_as_uint(f);
    return (ushort)((u + 0x7fffu + ((u >> 16) & 1u)) >> 16);   // RNE
}
__device__ __forceinline__ float bf2f(ushort h) {
    return __uint_as_float((uint)h << 16);
}
__device__ __forceinline__ uint pk2(float lo, float hi) {
    return (uint)f2bf(lo) | ((uint)f2bf(hi) << 16);
}
__device__ __forceinline__ short8 pack8(f32x4 a, f32x4 b) {
    uint4 r;
    r.x = pk2(a[0], a[1]); r.y = pk2(a[2], a[3]);
    r.z = pk2(b[0], b[1]); r.w = pk2(b[2], b[3]);
    union { uint4 u; short8 s; } cv; cv.u = r; return cv.s;
}

// ---------------------------------------------------------------------------
__global__ __launch_bounds__(256)
void prep_weights(const float* __restrict__ Wq, const float* __restrict__ Wn,
                  const float* __restrict__ Ww, const float* __restrict__ Wg,
                  ushort* __restrict__ WqT, ushort* __restrict__ WnT,
                  ushort* __restrict__ WwT, ushort* __restrict__ WgT)
{
    int idx = blockIdx.x * 256 + threadIdx.x;   // 320 blocks -> 81920
    const float* W; ushort* WT; int K; int j = idx;
    if (j < 16384)      { W = Wq; WT = WqT; K = 128; }
    else if (j < 32768) { W = Wn; WT = WnT; K = 128; j -= 16384; }
    else if (j < 65536) { W = Ww; WT = WwT; K = 256; j -= 32768; }
    else                { W = Wg; WT = WgT; K = 128; j -= 65536; }
    int n = j & 127, k = j >> 7;
    WT[(size_t)n * K + k] = f2bf(W[j]);
}

// ---------------------------------------------------------------------------
// K1: weight-stationary dual GEMM. One wave = one independent tile stream.
// wreg[ks][mt] lane l = WT[16mt+(l&15)][32ks+8(l>>4)+i]  (A-operand frag).
// afrag[ks]   lane l = Arow[tile*16+(l&15)][32ks+8(l>>4)+i] (B-operand frag).
// ---------------------------------------------------------------------------
__global__ __launch_bounds__(256, 2)
void k1_reg(const float* __restrict__ table, const int* __restrict__ node_ids,
            const ushort* __restrict__ WnT, const float* __restrict__ bn,
            const ushort* __restrict__ WqT, const float* __restrict__ bq,
            ushort* __restrict__ H, ushort* __restrict__ nh,
            int V, int N, int splitH)
{
    __shared__ float blds[128];
    const int tid = threadIdx.x;
    const int w = tid >> 6, l = tid & 63, l16 = l & 15, lh = l >> 4;
    const bool isH = (int)blockIdx.x < splitH;

    const ushort* WT = isH ? WnT : WqT;
    short8 wreg[4][8];
#pragma unroll
    for (int ks = 0; ks < 4; ++ks)
#pragma unroll
        for (int mt = 0; mt < 8; ++mt)
            wreg[ks][mt] = *reinterpret_cast<const short8*>(
                &WT[(size_t)(16 * mt + l16) * 128 + 32 * ks + 8 * lh]);
    if (tid < 128) blds[tid] = (isH ? bn : bq)[tid];
    __syncthreads();

    const int M   = isH ? V : N;
    ushort* out   = isH ? H : nh;
    const int ldo = isH ? 128 : 256;
    const int nt  = (M + 15) >> 4;
    const int wid    = (isH ? (int)blockIdx.x : (int)blockIdx.x - splitH) * 4 + w;
    const int nwaves = (isH ? splitH : (int)gridDim.x - splitH) * 4;

    for (int tile = wid; tile < nt; tile += nwaves) {
        const int row = tile * 16 + l16;
        int g = (row < M) ? row : (M - 1);
        if (!isH) g = node_ids[g];
        const float* rp = table + (size_t)g * 128 + 8 * lh;

        f32x4 f[8];
#pragma unroll
        for (int ks = 0; ks < 4; ++ks) {
            f[2 * ks]     = *reinterpret_cast<const f32x4*>(rp + 32 * ks);
            f[2 * ks + 1] = *reinterpret_cast<const f32x4*>(rp + 32 * ks + 4);
        }
        short8 a[4];
#pragma unroll
        for (int ks = 0; ks < 4; ++ks) a[ks] = pack8(f[2 * ks], f[2 * ks + 1]);

        f32x4 acc[8];
#pragma unroll
        for (int mt = 0; mt < 8; ++mt)
#pragma unroll
            for (int i = 0; i < 4; ++i) acc[mt][i] = 0.f;
#pragma unroll
        for (int ks = 0; ks < 4; ++ks)
#pragma unroll
            for (int mt = 0; mt < 8; ++mt)
                acc[mt] = __builtin_amdgcn_mfma_f32_16x16x32_bf16(
                    wreg[ks][mt], a[ks], acc[mt], 0, 0, 0);

        if (row < M) {
#pragma unroll
            for (int mt = 0; mt < 8; ++mt) {
                f32x4 bv = *reinterpret_cast<const f32x4*>(&blds[16 * mt + 4 * lh]);
                uint2 q;
                q.x = pk2(fmaxf(acc[mt][0] + bv[0], 0.f), fmaxf(acc[mt][1] + bv[1], 0.f));
                q.y = pk2(fmaxf(acc[mt][2] + bv[2], 0.f), fmaxf(acc[mt][3] + bv[3], 0.f));
                *reinterpret_cast<uint2*>(&out[(size_t)row * ldo + 16 * mt + 4 * lh]) = q;
            }
        }
    }
}

// ---------------------------------------------------------------------------
// K5: weight-stationary final GEMM. A bf16 (embb), out fp32, global scale.
// ---------------------------------------------------------------------------
__global__ __launch_bounds__(256, 2)
void k5_reg(const ushort* __restrict__ embb, const ushort* __restrict__ WgT,
            const float* __restrict__ bg, const float* __restrict__ scale_ptr,
            float* __restrict__ outp, int N)
{
    __shared__ float blds[128];
    const int tid = threadIdx.x;
    const int w = tid >> 6, l = tid & 63, l16 = l & 15, lh = l >> 4;

    short8 wreg[4][8];
#pragma unroll
    for (int ks = 0; ks < 4; ++ks)
#pragma unroll
        for (int mt = 0; mt < 8; ++mt)
            wreg[ks][mt] = *reinterpret_cast<const short8*>(
                &WgT[(size_t)(16 * mt + l16) * 128 + 32 * ks + 8 * lh]);
    if (tid < 128) blds[tid] = bg[tid];
    __syncthreads();
    const float scale = scale_ptr[0];

    const int nt = (N + 15) >> 4;
    const int wid = (int)blockIdx.x * 4 + w;
    const int nwaves = (int)gridDim.x * 4;

    for (int tile = wid; tile < nt; tile += nwaves) {
        const int row = tile * 16 + l16;
        const int g = (row < N) ? row : (N - 1);
        const ushort* rp = embb + (size_t)g * 128 + 8 * lh;

        short8 a[4];
#pragma unroll
        for (int ks = 0; ks < 4; ++ks)
            a[ks] = *reinterpret_cast<const short8*>(rp + 32 * ks);

        f32x4 acc[8];
#pragma unroll
        for (int mt = 0; mt < 8; ++mt)
#pragma unroll
            for (int i = 0; i < 4; ++i) acc[mt][i] = 0.f;
#pragma unroll
        for (int ks = 0; ks < 4; ++ks)
#pragma unroll
            for (int mt = 0; mt < 8; ++mt)
                acc[mt] = __builtin_amdgcn_mfma_f32_16x16x32_bf16(
                    wreg[ks][mt], a[ks], acc[mt], 0, 0, 0);

        if (row < N) {
#pragma unroll
            for (int mt = 0; mt < 8; ++mt) {
                f32x4 bv = *reinterpret_cast<const f32x4*>(&blds[16 * mt + 4 * lh]);
                f32x4 v;
#pragma unroll
                for (int i = 0; i < 4; ++i)
                    v[i] = fmaxf(fmaf(acc[mt][i], scale, bv[i]), 0.f);
                *reinterpret_cast<f32x4*>(&outp[(size_t)row * 128 + 16 * mt + 4 * lh]) = v;
            }
        }
    }
}

// ---------------------------------------------------------------------------
// K2: agg[n][:] = sum_t alpha[n,t] * H[neigh_ids[n,t]][:]
// ---------------------------------------------------------------------------
__global__ __launch_bounds__(256)
void agg_bf16(const ushort* __restrict__ H,
              const int* __restrict__ nids,
              const float* __restrict__ alpha,
              ushort* __restrict__ outb,     // nh + 128, row stride 256
              int N)
{
    const int n   = blockIdx.x * 16 + (threadIdx.x >> 4);
    const int l16 = threadIdx.x & 15;
    if (n >= N) return;

    const int*   idp = &nids[n * 20];
    const float* alp = &alpha[n * 20];
    float a[8];
#pragma unroll
    for (int j = 0; j < 8; ++j) a[j] = 0.f;
#pragma unroll
    for (int t = 0; t < 20; ++t) {
        const int   id = idp[t];
        const float al = alp[t];
        uint4 h = *reinterpret_cast<const uint4*>(&H[(size_t)id * 128 + 8 * l16]);
        a[0] = fmaf(al, bf2f((ushort)(h.x & 0xffff)), a[0]);
        a[1] = fmaf(al, bf2f((ushort)(h.x >> 16)),    a[1]);
        a[2] = fmaf(al, bf2f((ushort)(h.y & 0xffff)), a[2]);
        a[3] = fmaf(al, bf2f((ushort)(h.y >> 16)),    a[3]);
        a[4] = fmaf(al, bf2f((ushort)(h.z & 0xffff)), a[4]);
        a[5] = fmaf(al, bf2f((ushort)(h.z >> 16)),    a[5]);
        a[6] = fmaf(al, bf2f((ushort)(h.w & 0xffff)), a[6]);
        a[7] = fmaf(al, bf2f((ushort)(h.w >> 16)),    a[7]);
    }
    uint4 p;
    p.x = pk2(a[0], a[1]); p.y = pk2(a[2], a[3]);
    p.z = pk2(a[4], a[5]); p.w = pk2(a[6], a[7]);
    *reinterpret_cast<uint4*>(&outb[(size_t)n * 256 + 8 * l16]) = p;
}

// ---------------------------------------------------------------------------
// K3: r2/r5 LDS-staged MFMA GEMM, K=256 (W too large for registers).
// ---------------------------------------------------------------------------
__global__ __launch_bounds__(256, 2)
void k3_emb(const ushort* __restrict__ nh, const ushort* __restrict__ WT,
            const float* __restrict__ bias, ushort* __restrict__ embb,
            float* __restrict__ partials, int M)
{
    __shared__ __align__(16) char smem[65536];  // A: [0,32K)  B: [32K,64K)
    __shared__ float red[256];
    char* Bbase = smem + 32768;
    const int KTOT = 256, lda = 256, ldo = 128;

    const int tid = threadIdx.x;
    const int w   = tid >> 6;
    const int l   = tid & 63;
    const int l16 = l & 15, lh = l >> 4;
    const int brow = blockIdx.x * 128;

    f32x4 acc[2][8];
#pragma unroll
    for (int fr = 0; fr < 2; ++fr)
#pragma unroll
        for (int fc = 0; fc < 8; ++fc)
#pragma unroll
            for (int i = 0; i < 4; ++i) acc[fr][fc][i] = 0.f;

    for (int k0 = 0; k0 < KTOT; k0 += 128) {
#pragma unroll
        for (int it = 0; it < 8; ++it) {
            int idx = it * 256 + tid;
            int r = idx >> 4, o = idx & 15;
            int row = brow + r; int grow = (row < M) ? row : (M - 1);
            uint4 v = *reinterpret_cast<const uint4*>(&nh[(size_t)grow * lda + k0 + 8 * o]);
            *reinterpret_cast<uint4*>(smem + r * 256 + ((16 * o) ^ ((r & 7) << 4))) = v;
        }
#pragma unroll
        for (int it = 0; it < 8; ++it) {
            int idx = it * 256 + tid;
            int n = idx >> 4, o = idx & 15;
            uint4 v = *reinterpret_cast<const uint4*>(&WT[(size_t)n * KTOT + k0 + 8 * o]);
            *reinterpret_cast<uint4*>(Bbase + n * 256 + ((16 * o) ^ ((n & 7) << 4))) = v;
        }
        __syncthreads();

        const int r0 = 32 * w + l16;
        const int r1 = r0 + 16;
#pragma unroll
        for (int ks = 0; ks < 4; ++ks) {
            const int kb = 64 * ks + 16 * lh;
            short8 a0 = *reinterpret_cast<const short8*>(
                smem + r0 * 256 + (kb ^ ((r0 & 7) << 4)));
            short8 a1 = *reinterpret_cast<const short8*>(
                smem + r1 * 256 + (kb ^ ((r1 & 7) << 4)));
#pragma unroll
            for (int fc = 0; fc < 8; ++fc) {
                const int nn = 16 * fc + l16;
                short8 b = *reinterpret_cast<const short8*>(
                    Bbase + nn * 256 + (kb ^ ((nn & 7) << 4)));
                acc[0][fc] = __builtin_amdgcn_mfma_f32_16x16x32_bf16(a0, b, acc[0][fc], 0, 0, 0);
                acc[1][fc] = __builtin_amdgcn_mfma_f32_16x16x32_bf16(a1, b, acc[1][fc], 0, 0, 0);
            }
        }
        __syncthreads();
    }

    float bloc[8];
#pragma unroll
    for (int fc = 0; fc < 8; ++fc) bloc[fc] = bias[16 * fc + l16];

    float ssq = 0.f;
#pragma unroll
    for (int fr = 0; fr < 2; ++fr)
#pragma unroll
        for (int fc = 0; fc < 8; ++fc)
#pragma unroll
            for (int i = 0; i < 4; ++i) {
                const int r   = 32 * w + 16 * fr + 4 * lh + i;
                const int col = 16 * fc + l16;
                float v = fmaxf(acc[fr][fc][i] + bloc[fc], 0.f);
                if (brow + r < M) ssq += v * v;
                ((ushort*)smem)[r * 128 + col] = f2bf(v);
            }
    __syncthreads();

#pragma unroll
    for (int it = 0; it < 8; ++it) {
        int idx = it * 256 + tid;
        int r = idx >> 4, o = idx & 15;
        if (brow + r < M)
            *reinterpret_cast<uint4*>(&embb[(size_t)(brow + r) * ldo + 8 * o]) =
                *reinterpret_cast<const uint4*>((ushort*)smem + r * 128 + 8 * o);
    }

    red[tid] = ssq;
    __syncthreads();
    for (int st = 128; st > 0; st >>= 1) {
        if (tid < st) red[tid] += red[tid + st];
        __syncthreads();
    }
    if (tid == 0) partials[blockIdx.x] = red[0];
}

// ---------------------------------------------------------------------------
__global__ void reduce_norm(const float* __restrict__ partials, int n,
                            float* __restrict__ scale)
{
    __shared__ float red[256];
    float s = 0.f;
    for (int i = threadIdx.x; i < n; i += 256) s += partials[i];
    red[threadIdx.x] = s;
    __syncthreads();
    for (int st = 128; st > 0; st >>= 1) {
        if (threadIdx.x < st) red[threadIdx.x] += red[threadIdx.x + st];
        __syncthreads();
    }
    if (threadIdx.x == 0) scale[0] = 1.0f / sqrtf(red[0]);
}

// ---------------------------------------------------------------------------
extern "C" void kernel_launch(void* const* d_in, const int* in_sizes, int n_in,
                              void* d_out, int out_size, void* d_ws, size_t ws_size,
                              hipStream_t stream)
{
    const int*   node_ids  = (const int*)  d_in[0];
    const int*   neigh_ids = (const int*)  d_in[1];
    const float* alpha     = (const float*)d_in[2];
    const float* table     = (const float*)d_in[3];
    const float* Wq        = (const float*)d_in[4];
    const float* bq        = (const float*)d_in[5];
    const float* Wn        = (const float*)d_in[6];
    const float* bn        = (const float*)d_in[7];
    const float* Ww        = (const float*)d_in[8];
    const float* bw        = (const float*)d_in[9];
    const float* Wg        = (const float*)d_in[10];
    const float* bg        = (const float*)d_in[11];

    const int N = in_sizes[0];            // 50000
    const int V = in_sizes[3] / 128;      // 200000
    float* out = (float*)d_out;

    // workspace layout
    ushort* H    = (ushort*)d_ws;                 // [V][128] bf16
    ushort* nh   = H    + (size_t)V * 128;        // [N][256] = [node_h | agg]
    ushort* embb = nh   + (size_t)N * 256;        // [N][128]
    ushort* WqT  = embb + (size_t)N * 128;
    ushort* WnT  = WqT  + 16384;
    ushort* WwT  = WnT  + 16384;
    ushort* WgT  = WwT  + 32768;
    float*  partials = (float*)(WgT + 16384);     // 512
    float*  scale    = partials + 512;

    const size_t need = (size_t)((char*)(scale + 16) - (char*)d_ws);
    if (ws_size < need) return;

    const int nblkN = (N + 127) / 128;

    // K1 grid: 512 blocks (2/CU, VGPR-limited), split by 16-row tile counts
    const int G1 = 512;
    const long long tH = (V + 15) / 16, tN = (N + 15) / 16;
    int splitH = (int)((G1 * tH) / (tH + tN));
    if (splitH < 1) splitH = 1;
    if (splitH > G1 - 1) splitH = G1 - 1;

    prep_weights<<<320, 256, 0, stream>>>(Wq, Wn, Ww, Wg, WqT, WnT, WwT, WgT);
    k1_reg<<<G1, 256, 0, stream>>>(table, node_ids, WnT, bn, WqT, bq,
                                   H, nh, V, N, splitH);
    agg_bf16<<<(N + 15) / 16, 256, 0, stream>>>(H, neigh_ids, alpha, nh + 128, N);
    k3_emb<<<nblkN, 256, 0, stream>>>(nh, WwT, bw, embb, partials, N);
    reduce_norm<<<1, 256, 0, stream>>>(partials, nblkN, scale);
    k5_reg<<<256, 256, 0, stream>>>(embb, WgT, bg, scale, out, N);
}

// Round 7
// 113.058 us; speedup vs baseline: 1.0366x; 1.0366x over previous
//
#include <hip/hip_runtime.h>
#include <math.h>

// PinSAGE fused pipeline, r7: r6 weight-stationary K1/K5 + asm-pinned W
// registers (defeat remat), explicit next-tile A prefetch, reduce_norm
// folded into K5.  D=U=E=128, T=20 fixed; N, V from in_sizes.
//
// K0 prep:   WqT/WnT/WwT/WgT = bf16 transpose of weights (WT[n][k])
// K1 reg:    H = relu(table @ Wn + bn) -> bf16 [V][128]   (blocks < splitH)
//            nodeh = relu(table[node_ids] @ Wq + bq) -> nh[:,0:128] (rest)
//            W in 128 VGPRs (32 frags, asm-pinned), wave-autonomous 16-row
//            tiles, no LDS/barriers in loop, line-coalesced direct loads.
// K2 agg:    nh[:,128:256] = sum_t alpha * H[neigh]       (gather-FMA)
// K3 emb:    embb = relu(nh @ Ww + bw) bf16 + sumsq partials (LDS-staged)
// K4 reg:    out = relu(scale*(embb @ Wg) + bg) fp32; scale from inline
//            per-block reduction of partials (no separate norm kernel).
//
// MFMA orientation (verified r3/r5/r6): acc[mt] = mfma(wfrag, afrag, acc) ->
// lane l holds C[row = tile*16 + (l&15)][cols 16*mt + 4*(l>>4) + i].

using f32x4  = __attribute__((ext_vector_type(4))) float;
using short8 = __attribute__((ext_vector_type(8))) short;   // 8 bf16

__device__ __forceinline__ ushort f2bf(float f) {
    uint u = __float_as_uint(f);
    return (ushort)((u + 0x7fffu + ((u >> 16) & 1u)) >> 16);   // RNE
}
__device__ __forceinline__ float bf2f(ushort h) {
    return __uint_as_float((uint)h << 16);
}
__device__ __forceinline__ uint pk2(float lo, float hi) {
    return (uint)f2bf(lo) | ((uint)f2bf(hi) << 16);
}
__device__ __forceinline__ short8 pack8(f32x4 a, f32x4 b) {
    uint4 r;
    r.x = pk2(a[0], a[1]); r.y = pk2(a[2], a[3]);
    r.z = pk2(b[0], b[1]); r.w = pk2(b[2], b[3]);
    union { uint4 u; short8 s; } cv; cv.u = r; return cv.s;
}

// ---------------------------------------------------------------------------
__global__ __launch_bounds__(256)
void prep_weights(const float* __restrict__ Wq, const float* __restrict__ Wn,
                  const float* __restrict__ Ww, const float* __restrict__ Wg,
                  ushort* __restrict__ WqT, ushort* __restrict__ WnT,
                  ushort* __restrict__ WwT, ushort* __restrict__ WgT)
{
    int idx = blockIdx.x * 256 + threadIdx.x;   // 320 blocks -> 81920
    const float* W; ushort* WT; int K; int j = idx;
    if (j < 16384)      { W = Wq; WT = WqT; K = 128; }
    else if (j < 32768) { W = Wn; WT = WnT; K = 128; j -= 16384; }
    else if (j < 65536) { W = Ww; WT = WwT; K = 256; j -= 32768; }
    else                { W = Wg; WT = WgT; K = 128; j -= 65536; }
    int n = j & 127, k = j >> 7;
    WT[(size_t)n * K + k] = f2bf(W[j]);
}

// ---------------------------------------------------------------------------
// Load 32 W fragments into registers and PIN them (opaque asm redefinition:
// the value no longer comes from a load, so regalloc cannot rematerialize).
// ---------------------------------------------------------------------------
__device__ __forceinline__ void load_wreg_pinned(const ushort* __restrict__ WT,
                                                 short8 (&wreg)[4][8],
                                                 int l16, int lh)
{
#pragma unroll
    for (int ks = 0; ks < 4; ++ks)
#pragma unroll
        for (int mt = 0; mt < 8; ++mt)
            wreg[ks][mt] = *reinterpret_cast<const short8*>(
                &WT[(size_t)(16 * mt + l16) * 128 + 32 * ks + 8 * lh]);
#pragma unroll
    for (int ks = 0; ks < 4; ++ks)
#pragma unroll
        for (int mt = 0; mt < 8; ++mt)
            asm volatile("" : "+v"(wreg[ks][mt]));
}

// ---------------------------------------------------------------------------
// K1: weight-stationary dual GEMM. One wave = one independent tile stream.
// ---------------------------------------------------------------------------
__global__ __launch_bounds__(256, 2)
void k1_reg(const float* __restrict__ table, const int* __restrict__ node_ids,
            const ushort* __restrict__ WnT, const float* __restrict__ bn,
            const ushort* __restrict__ WqT, const float* __restrict__ bq,
            ushort* __restrict__ H, ushort* __restrict__ nh,
            int V, int N, int splitH)
{
    __shared__ float blds[128];
    const int tid = threadIdx.x;
    const int w = tid >> 6, l = tid & 63, l16 = l & 15, lh = l >> 4;
    const bool isH = (int)blockIdx.x < splitH;

    short8 wreg[4][8];
    load_wreg_pinned(isH ? WnT : WqT, wreg, l16, lh);
    if (tid < 128) blds[tid] = (isH ? bn : bq)[tid];
    __syncthreads();

    const int M   = isH ? V : N;
    ushort* out   = isH ? H : nh;
    const int ldo = isH ? 128 : 256;
    const int nt  = (M + 15) >> 4;
    const int wid    = (isH ? (int)blockIdx.x : (int)blockIdx.x - splitH) * 4 + w;
    const int nwaves = (isH ? splitH : (int)gridDim.x - splitH) * 4;
    if (wid >= nt) return;

    // prologue: issue loads for first tile
    f32x4 f[8];
    {
        const int row = wid * 16 + l16;
        int g = (row < M) ? row : (M - 1);
        if (!isH) g = node_ids[g];
        const float* rp = table + (size_t)g * 128 + 8 * lh;
#pragma unroll
        for (int ks = 0; ks < 4; ++ks) {
            f[2 * ks]     = *reinterpret_cast<const f32x4*>(rp + 32 * ks);
            f[2 * ks + 1] = *reinterpret_cast<const f32x4*>(rp + 32 * ks + 4);
        }
    }

    for (int tile = wid; tile < nt; tile += nwaves) {
        // pack current tile (waits the in-flight loads)
        short8 a[4];
#pragma unroll
        for (int ks = 0; ks < 4; ++ks) a[ks] = pack8(f[2 * ks], f[2 * ks + 1]);

        // issue next tile's loads BEFORE the MFMA block (prefetch)
        const int nxt = tile + nwaves;
        if (nxt < nt) {
            const int row = nxt * 16 + l16;
            int g = (row < M) ? row : (M - 1);
            if (!isH) g = node_ids[g];
            const float* rp = table + (size_t)g * 128 + 8 * lh;
#pragma unroll
            for (int ks = 0; ks < 4; ++ks) {
                f[2 * ks]     = *reinterpret_cast<const f32x4*>(rp + 32 * ks);
                f[2 * ks + 1] = *reinterpret_cast<const f32x4*>(rp + 32 * ks + 4);
            }
        }

        f32x4 acc[8];
#pragma unroll
        for (int mt = 0; mt < 8; ++mt)
#pragma unroll
            for (int i = 0; i < 4; ++i) acc[mt][i] = 0.f;
#pragma unroll
        for (int ks = 0; ks < 4; ++ks)
#pragma unroll
            for (int mt = 0; mt < 8; ++mt)
                acc[mt] = __builtin_amdgcn_mfma_f32_16x16x32_bf16(
                    wreg[ks][mt], a[ks], acc[mt], 0, 0, 0);

        const int row = tile * 16 + l16;
        if (row < M) {
#pragma unroll
            for (int mt = 0; mt < 8; ++mt) {
                f32x4 bv = *reinterpret_cast<const f32x4*>(&blds[16 * mt + 4 * lh]);
                uint2 q;
                q.x = pk2(fmaxf(acc[mt][0] + bv[0], 0.f), fmaxf(acc[mt][1] + bv[1], 0.f));
                q.y = pk2(fmaxf(acc[mt][2] + bv[2], 0.f), fmaxf(acc[mt][3] + bv[3], 0.f));
                *reinterpret_cast<uint2*>(&out[(size_t)row * ldo + 16 * mt + 4 * lh]) = q;
            }
        }
    }
}

// ---------------------------------------------------------------------------
// K4: weight-stationary final GEMM + inline norm reduction.
// ---------------------------------------------------------------------------
__global__ __launch_bounds__(256, 2)
void k4_final(const ushort* __restrict__ embb, const ushort* __restrict__ WgT,
              const float* __restrict__ bg, const float* __restrict__ partials,
              int P, float* __restrict__ outp, int N)
{
    __shared__ float blds[128];
    __shared__ float red[256];
    __shared__ float s_scale;
    const int tid = threadIdx.x;
    const int w = tid >> 6, l = tid & 63, l16 = l & 15, lh = l >> 4;

    short8 wreg[4][8];
    load_wreg_pinned(WgT, wreg, l16, lh);
    if (tid < 128) blds[tid] = bg[tid];

    float s = 0.f;
    for (int i = tid; i < P; i += 256) s += partials[i];
    red[tid] = s;
    __syncthreads();
    for (int st = 128; st > 0; st >>= 1) {
        if (tid < st) red[tid] += red[tid + st];
        __syncthreads();
    }
    if (tid == 0) s_scale = 1.0f / sqrtf(red[0]);
    __syncthreads();
    const float scale = s_scale;

    const int nt = (N + 15) >> 4;
    const int wid = (int)blockIdx.x * 4 + w;
    const int nwaves = (int)gridDim.x * 4;
    if (wid >= nt) return;

    short8 a[4];
    {
        const int row = wid * 16 + l16;
        const int g = (row < N) ? row : (N - 1);
        const ushort* rp = embb + (size_t)g * 128 + 8 * lh;
#pragma unroll
        for (int ks = 0; ks < 4; ++ks)
            a[ks] = *reinterpret_cast<const short8*>(rp + 32 * ks);
    }

    for (int tile = wid; tile < nt; tile += nwaves) {
        short8 cur[4];
#pragma unroll
        for (int ks = 0; ks < 4; ++ks) cur[ks] = a[ks];

        const int nxt = tile + nwaves;
        if (nxt < nt) {
            const int row = nxt * 16 + l16;
            const int g = (row < N) ? row : (N - 1);
            const ushort* rp = embb + (size_t)g * 128 + 8 * lh;
#pragma unroll
            for (int ks = 0; ks < 4; ++ks)
                a[ks] = *reinterpret_cast<const short8*>(rp + 32 * ks);
        }

        f32x4 acc[8];
#pragma unroll
        for (int mt = 0; mt < 8; ++mt)
#pragma unroll
            for (int i = 0; i < 4; ++i) acc[mt][i] = 0.f;
#pragma unroll
        for (int ks = 0; ks < 4; ++ks)
#pragma unroll
            for (int mt = 0; mt < 8; ++mt)
                acc[mt] = __builtin_amdgcn_mfma_f32_16x16x32_bf16(
                    wreg[ks][mt], cur[ks], acc[mt], 0, 0, 0);

        const int row = tile * 16 + l16;
        if (row < N) {
#pragma unroll
            for (int mt = 0; mt < 8; ++mt) {
                f32x4 bv = *reinterpret_cast<const f32x4*>(&blds[16 * mt + 4 * lh]);
                f32x4 v;
#pragma unroll
                for (int i = 0; i < 4; ++i)
                    v[i] = fmaxf(fmaf(acc[mt][i], scale, bv[i]), 0.f);
                *reinterpret_cast<f32x4*>(&outp[(size_t)row * 128 + 16 * mt + 4 * lh]) = v;
            }
        }
    }
}

// ---------------------------------------------------------------------------
// K2: agg[n][:] = sum_t alpha[n,t] * H[neigh_ids[n,t]][:]
// ---------------------------------------------------------------------------
__global__ __launch_bounds__(256)
void agg_bf16(const ushort* __restrict__ H,
              const int* __restrict__ nids,
              const float* __restrict__ alpha,
              ushort* __restrict__ outb,     // nh + 128, row stride 256
              int N)
{
    const int n   = blockIdx.x * 16 + (threadIdx.x >> 4);
    const int l16 = threadIdx.x & 15;
    if (n >= N) return;

    const int*   idp = &nids[n * 20];
    const float* alp = &alpha[n * 20];
    float a[8];
#pragma unroll
    for (int j = 0; j < 8; ++j) a[j] = 0.f;
#pragma unroll
    for (int t = 0; t < 20; ++t) {
        const int   id = idp[t];
        const float al = alp[t];
        uint4 h = *reinterpret_cast<const uint4*>(&H[(size_t)id * 128 + 8 * l16]);
        a[0] = fmaf(al, bf2f((ushort)(h.x & 0xffff)), a[0]);
        a[1] = fmaf(al, bf2f((ushort)(h.x >> 16)),    a[1]);
        a[2] = fmaf(al, bf2f((ushort)(h.y & 0xffff)), a[2]);
        a[3] = fmaf(al, bf2f((ushort)(h.y >> 16)),    a[3]);
        a[4] = fmaf(al, bf2f((ushort)(h.z & 0xffff)), a[4]);
        a[5] = fmaf(al, bf2f((ushort)(h.z >> 16)),    a[5]);
        a[6] = fmaf(al, bf2f((ushort)(h.w & 0xffff)), a[6]);
        a[7] = fmaf(al, bf2f((ushort)(h.w >> 16)),    a[7]);
    }
    uint4 p;
    p.x = pk2(a[0], a[1]); p.y = pk2(a[2], a[3]);
    p.z = pk2(a[4], a[5]); p.w = pk2(a[6], a[7]);
    *reinterpret_cast<uint4*>(&outb[(size_t)n * 256 + 8 * l16]) = p;
}

// ---------------------------------------------------------------------------
// K3: LDS-staged MFMA GEMM, K=256 (W too large for registers).
// ---------------------------------------------------------------------------
__global__ __launch_bounds__(256, 2)
void k3_emb(const ushort* __restrict__ nh, const ushort* __restrict__ WT,
            const float* __restrict__ bias, ushort* __restrict__ embb,
            float* __restrict__ partials, int M)
{
    __shared__ __align__(16) char smem[65536];  // A: [0,32K)  B: [32K,64K)
    __shared__ float red[256];
    char* Bbase = smem + 32768;
    const int KTOT = 256, lda = 256, ldo = 128;

    const int tid = threadIdx.x;
    const int w   = tid >> 6;
    const int l   = tid & 63;
    const int l16 = l & 15, lh = l >> 4;
    const int brow = blockIdx.x * 128;

    f32x4 acc[2][8];
#pragma unroll
    for (int fr = 0; fr < 2; ++fr)
#pragma unroll
        for (int fc = 0; fc < 8; ++fc)
#pragma unroll
            for (int i = 0; i < 4; ++i) acc[fr][fc][i] = 0.f;

    for (int k0 = 0; k0 < KTOT; k0 += 128) {
#pragma unroll
        for (int it = 0; it < 8; ++it) {
            int idx = it * 256 + tid;
            int r = idx >> 4, o = idx & 15;
            int row = brow + r; int grow = (row < M) ? row : (M - 1);
            uint4 v = *reinterpret_cast<const uint4*>(&nh[(size_t)grow * lda + k0 + 8 * o]);
            *reinterpret_cast<uint4*>(smem + r * 256 + ((16 * o) ^ ((r & 7) << 4))) = v;
        }
#pragma unroll
        for (int it = 0; it < 8; ++it) {
            int idx = it * 256 + tid;
            int n = idx >> 4, o = idx & 15;
            uint4 v = *reinterpret_cast<const uint4*>(&WT[(size_t)n * KTOT + k0 + 8 * o]);
            *reinterpret_cast<uint4*>(Bbase + n * 256 + ((16 * o) ^ ((n & 7) << 4))) = v;
        }
        __syncthreads();

        const int r0 = 32 * w + l16;
        const int r1 = r0 + 16;
#pragma unroll
        for (int ks = 0; ks < 4; ++ks) {
            const int kb = 64 * ks + 16 * lh;
            short8 a0 = *reinterpret_cast<const short8*>(
                smem + r0 * 256 + (kb ^ ((r0 & 7) << 4)));
            short8 a1 = *reinterpret_cast<const short8*>(
                smem + r1 * 256 + (kb ^ ((r1 & 7) << 4)));
#pragma unroll
            for (int fc = 0; fc < 8; ++fc) {
                const int nn = 16 * fc + l16;
                short8 b = *reinterpret_cast<const short8*>(
                    Bbase + nn * 256 + (kb ^ ((nn & 7) << 4)));
                acc[0][fc] = __builtin_amdgcn_mfma_f32_16x16x32_bf16(a0, b, acc[0][fc], 0, 0, 0);
                acc[1][fc] = __builtin_amdgcn_mfma_f32_16x16x32_bf16(a1, b, acc[1][fc], 0, 0, 0);
            }
        }
        __syncthreads();
    }

    float bloc[8];
#pragma unroll
    for (int fc = 0; fc < 8; ++fc) bloc[fc] = bias[16 * fc + l16];

    float ssq = 0.f;
#pragma unroll
    for (int fr = 0; fr < 2; ++fr)
#pragma unroll
        for (int fc = 0; fc < 8; ++fc)
#pragma unroll
            for (int i = 0; i < 4; ++i) {
                const int r   = 32 * w + 16 * fr + 4 * lh + i;
                const int col = 16 * fc + l16;
                float v = fmaxf(acc[fr][fc][i] + bloc[fc], 0.f);
                if (brow + r < M) ssq += v * v;
                ((ushort*)smem)[r * 128 + col] = f2bf(v);
            }
    __syncthreads();

#pragma unroll
    for (int it = 0; it < 8; ++it) {
        int idx = it * 256 + tid;
        int r = idx >> 4, o = idx & 15;
        if (brow + r < M)
            *reinterpret_cast<uint4*>(&embb[(size_t)(brow + r) * ldo + 8 * o]) =
                *reinterpret_cast<const uint4*>((ushort*)smem + r * 128 + 8 * o);
    }

    red[tid] = ssq;
    __syncthreads();
    for (int st = 128; st > 0; st >>= 1) {
        if (tid < st) red[tid] += red[tid + st];
        __syncthreads();
    }
    if (tid == 0) partials[blockIdx.x] = red[0];
}

// ---------------------------------------------------------------------------
extern "C" void kernel_launch(void* const* d_in, const int* in_sizes, int n_in,
                              void* d_out, int out_size, void* d_ws, size_t ws_size,
                              hipStream_t stream)
{
    const int*   node_ids  = (const int*)  d_in[0];
    const int*   neigh_ids = (const int*)  d_in[1];
    const float* alpha     = (const float*)d_in[2];
    const float* table     = (const float*)d_in[3];
    const float* Wq        = (const float*)d_in[4];
    const float* bq        = (const float*)d_in[5];
    const float* Wn        = (const float*)d_in[6];
    const float* bn        = (const float*)d_in[7];
    const float* Ww        = (const float*)d_in[8];
    const float* bw        = (const float*)d_in[9];
    const float* Wg        = (const float*)d_in[10];
    const float* bg        = (const float*)d_in[11];

    const int N = in_sizes[0];            // 50000
    const int V = in_sizes[3] / 128;      // 200000
    float* out = (float*)d_out;

    // workspace layout
    ushort* H    = (ushort*)d_ws;                 // [V][128] bf16
    ushort* nh   = H    + (size_t)V * 128;        // [N][256] = [node_h | agg]
    ushort* embb = nh   + (size_t)N * 256;        // [N][128]
    ushort* WqT  = embb + (size_t)N * 128;
    ushort* WnT  = WqT  + 16384;
    ushort* WwT  = WnT  + 16384;
    ushort* WgT  = WwT  + 32768;
    float*  partials = (float*)(WgT + 16384);     // 512
    float*  scale    = partials + 512;

    const size_t need = (size_t)((char*)(scale + 16) - (char*)d_ws);
    if (ws_size < need) return;

    const int nblkN = (N + 127) / 128;

    // K1 grid: 512 blocks (2/CU at ~240 VGPR), split by 16-row tile counts
    const int G1 = 512;
    const long long tH = (V + 15) / 16, tN = (N + 15) / 16;
    int splitH = (int)((G1 * tH) / (tH + tN));
    if (splitH < 1) splitH = 1;
    if (splitH > G1 - 1) splitH = G1 - 1;

    prep_weights<<<320, 256, 0, stream>>>(Wq, Wn, Ww, Wg, WqT, WnT, WwT, WgT);
    k1_reg<<<G1, 256, 0, stream>>>(table, node_ids, WnT, bn, WqT, bq,
                                   H, nh, V, N, splitH);
    agg_bf16<<<(N + 15) / 16, 256, 0, stream>>>(H, neigh_ids, alpha, nh + 128, N);
    k3_emb<<<nblkN, 256, 0, stream>>>(nh, WwT, bw, embb, partials, N);
    k4_final<<<256, 256, 0, stream>>>(embb, WgT, bg, partials, nblkN, out, N);
}